// Round 1
// baseline (1627.658 us; speedup 1.0000x reference)
//
#include <hip/hip_runtime.h>
#include <math.h>

#define Bb    32
#define Nn    4096
#define HISTC 16
#define PREDC 8
#define TTC   24
#define HIDC  32
#define EC    65536
#define BN    (Bb*Nn)          // 131072 = 2^17
#define WT_STRIDE 36           // 144B row stride: 16B aligned, bank-spread across q
#define GEX_STRIDE 148

__device__ __forceinline__ float sigm(float x){ return 1.f/(1.f+expf(-x)); }

// ---------------- CSR build ----------------
__global__ void k_deg(const int* __restrict__ ei, int* deg, int* cnt){
  int e = blockIdx.x*blockDim.x + threadIdx.x;
  if (e < EC){ atomicAdd(&deg[ei[e]],1); atomicAdd(&cnt[ei[EC+e]],1); }
}
__global__ void k_dis(const int* __restrict__ deg, float* dis){
  int n = blockIdx.x*blockDim.x + threadIdx.x;
  if (n < Nn) dis[n] = deg[n] > 0 ? rsqrtf((float)deg[n]) : 0.f;
}
__global__ void k_scan(const int* __restrict__ cnt, int* ptr){
  __shared__ int sd[1024];
  int t = threadIdx.x;
  int c0=cnt[4*t], c1=cnt[4*t+1], c2=cnt[4*t+2], c3=cnt[4*t+3];
  int s = c0+c1+c2+c3;
  sd[t] = s; __syncthreads();
  for (int off=1; off<1024; off<<=1){
    int v = (t>=off) ? sd[t-off] : 0;
    __syncthreads();
    sd[t] += v;
    __syncthreads();
  }
  int excl = sd[t]-s;
  ptr[4*t]=excl; ptr[4*t+1]=excl+c0; ptr[4*t+2]=excl+c0+c1; ptr[4*t+3]=excl+c0+c1+c2;
  if (t==1023) ptr[4096]=sd[1023];
}
__global__ void k_fill(const int* __restrict__ ei, const float* __restrict__ dis,
                       const int* __restrict__ ptr, int* fillc, int* csrc, float* cnrm){
  int e = blockIdx.x*blockDim.x + threadIdx.x;
  if (e < EC){
    int s = ei[e], d = ei[EC+e];
    int pos = ptr[d] + atomicAdd(&fillc[d],1);
    csrc[pos] = s;
    cnrm[pos] = -dis[s]*dis[d];
  }
}

// ---------------- z = x@W1, s = x@W0 + b ----------------
// hist: rows = 16*B*N (t = r>>17); pred: rows = B*N, t = t0, x0 from xn
template<bool PREDP>
__global__ void k_zs(const float* __restrict__ pm25, const float* __restrict__ xn,
                     const float* __restrict__ feat,
                     const float* __restrict__ cw, const float* __restrict__ cb,
                     float* __restrict__ z, float* __restrict__ s, int t0){
  int r = blockIdx.x*blockDim.x + threadIdx.x;
  int t, bn;
  if (PREDP){ t = t0; bn = r; } else { t = r >> 17; bn = r & (BN-1); }
  int b = bn >> 12, n = bn & (Nn-1);
  float x[10];
  x[0] = PREDP ? xn[bn] : pm25[(b*HISTC + t)*Nn + n];
  const float* fp = feat + ((size_t)(b*TTC + t)*Nn + n)*9;
  #pragma unroll
  for (int f=0; f<9; ++f) x[1+f] = fp[f];
  float z0=0.f, z1=0.f, s0=cb[0], s1=cb[1];
  #pragma unroll
  for (int f=0; f<10; ++f){
    s0 += x[f]*cw[f*2+0];      s1 += x[f]*cw[f*2+1];
    z0 += x[f]*cw[20+f*2+0];   z1 += x[f]*cw[20+f*2+1];
  }
  z[(size_t)r*2]   = z0; z[(size_t)r*2+1] = z1;
  s[(size_t)r*2]   = s0; s[(size_t)r*2+1] = s1;
}

// ---------------- agg gather + xg = sigmoid(s+agg), in-place into s ----------------
__global__ void k_agg(const int* __restrict__ ptr, const int* __restrict__ csrc,
                      const float* __restrict__ cnrm,
                      const float* __restrict__ z, float* __restrict__ s){
  int r = blockIdx.x*blockDim.x + threadIdx.x;
  int n  = r & (Nn-1);
  int tb = r >> 12;
  const float* zb = z + ((size_t)tb*Nn)*2;
  int p0 = ptr[n], p1 = ptr[n+1];
  float a0=0.f, a1=0.f;
  for (int i=p0; i<p1; ++i){
    int sidx = csrc[i]; float w = cnrm[i];
    a0 += w*zb[sidx*2]; a1 += w*zb[sidx*2+1];
  }
  float v0 = s[(size_t)r*2] + a0, v1 = s[(size_t)r*2+1] + a1;
  s[(size_t)r*2]   = 1.f/(1.f+expf(-v0));
  s[(size_t)r*2+1] = 1.f/(1.f+expf(-v1));
}

// ---------------- one LSTM step: 256 thr = 64 rows, 4 thr/row ----------------
template<bool PREDP>
__global__ __launch_bounds__(256,2)
void k_step(const float* __restrict__ pm25, const float* __restrict__ feat,
            const float* __restrict__ xg,
            const float* __restrict__ x2h_w, const float* __restrict__ x2h_b,
            const float* __restrict__ h2h_w, const float* __restrict__ h2h_b,
            const float* __restrict__ fc_w, const float* __restrict__ fc_b,
            float* __restrict__ h, float* __restrict__ c,
            float* __restrict__ xn, float* __restrict__ out,
            int t, int write_xn){
  __shared__ float s_wt[44*4*WT_STRIDE];
  __shared__ float s_b[128];
  __shared__ float s_gex[64*GEX_STRIDE];
  int tid = threadIdx.x;
  for (int e = tid; e < 44*128; e += 256){
    int k = e >> 7, col = e & 127;
    int q = col >> 5, j = col & 31;
    float w = (k < 12) ? x2h_w[e] : h2h_w[e - 12*128];
    s_wt[(k*4+q)*WT_STRIDE + j] = w;
  }
  if (tid < 128) s_b[tid] = x2h_b[tid] + h2h_b[tid];
  __syncthreads();

  int row = tid >> 2, q = tid & 3;
  int gr = blockIdx.x*64 + row;        // b*N + n
  int b = gr >> 12, n = gr & (Nn-1);

  float inv[12];
  inv[0] = PREDP ? xn[gr] : pm25[(b*HISTC + t)*Nn + n];
  const float* fp = feat + ((size_t)(b*TTC + t)*Nn + n)*9;
  #pragma unroll
  for (int f=0; f<9; ++f) inv[1+f] = fp[f];
  inv[10] = xg[(size_t)gr*2];
  inv[11] = xg[(size_t)gr*2+1];

  float acc[32];
  #pragma unroll
  for (int j=0; j<32; ++j) acc[j] = s_b[q*32+j];
  #pragma unroll
  for (int k=0; k<12; ++k){
    float v = inv[k];
    const float* wr = &s_wt[(k*4+q)*WT_STRIDE];
    #pragma unroll
    for (int j=0; j<32; ++j) acc[j] += v*wr[j];
  }
  const float4* hp = (const float4*)(h + (size_t)gr*32);
  #pragma unroll
  for (int v4=0; v4<8; ++v4){
    float4 h4 = hp[v4];
    float hvv[4] = {h4.x, h4.y, h4.z, h4.w};
    #pragma unroll
    for (int kk=0; kk<4; ++kk){
      float v = hvv[kk];
      const float* wr = &s_wt[((12+4*v4+kk)*4+q)*WT_STRIDE];
      #pragma unroll
      for (int j=0; j<32; ++j) acc[j] += v*wr[j];
    }
  }
  // exchange i/f/g/o across the 4 threads of the row
  {
    float* gx = &s_gex[row*GEX_STRIDE + q*36];
    #pragma unroll
    for (int j=0; j<32; ++j) gx[j] = acc[j];
  }
  __syncthreads();
  int u0 = q*8;
  const float* ge = &s_gex[row*GEX_STRIDE];
  float* cp = c + (size_t)gr*32 + u0;
  float* hq = h + (size_t)gr*32 + u0;
  float hn[8];
  #pragma unroll
  for (int u=0; u<8; ++u){
    float iv = ge[0*36 + u0+u];
    float fv = ge[1*36 + u0+u];
    float gv = ge[2*36 + u0+u];
    float ov = ge[3*36 + u0+u];
    float cc = sigm(fv)*cp[u] + sigm(iv)*tanhf(gv);
    cp[u] = cc;
    hn[u] = sigm(ov)*tanhf(cc);
  }
  #pragma unroll
  for (int u=0; u<8; ++u) hq[u] = hn[u];
  if (write_xn){
    float part = 0.f;
    #pragma unroll
    for (int u=0; u<8; ++u) part += hn[u]*fc_w[u0+u];
    part += __shfl_down(part, 2, 4);
    part += __shfl_down(part, 1, 4);
    if (q == 0){
      float r = part + fc_b[0];
      xn[gr] = r;
      if (out) out[(size_t)b*PREDC*Nn + n] = r;   // out pre-offset by tp*Nn
    }
  }
}

// ---------------- host ----------------
extern "C" void kernel_launch(void* const* d_in, const int* in_sizes, int n_in,
                              void* d_out, int out_size, void* d_ws, size_t ws_size,
                              hipStream_t stream){
  const float* pm25 = (const float*)d_in[0];
  const float* feat = (const float*)d_in[1];
  const int*   ei   = (const int*)d_in[2];
  const float* cw   = (const float*)d_in[3];
  const float* cb   = (const float*)d_in[4];
  const float* x2hw = (const float*)d_in[5];
  const float* x2hb = (const float*)d_in[6];
  const float* h2hw = (const float*)d_in[7];
  const float* h2hb = (const float*)d_in[8];
  const float* fcw  = (const float*)d_in[9];
  const float* fcb  = (const float*)d_in[10];
  float* out = (float*)d_out;

  char* w = (char*)d_ws;
  size_t off = 0;
  auto take = [&](size_t bytes)->char*{
    char* r = w + off; off += (bytes + 255) & ~(size_t)255; return r;
  };
  int*   deg   = (int*)  take(Nn*4);
  int*   cnt   = (int*)  take(Nn*4);
  int*   fillc = (int*)  take(Nn*4);
  int*   ptr   = (int*)  take((Nn+1)*4);
  float* dis   = (float*)take(Nn*4);
  int*   csrc  = (int*)  take(EC*4);
  float* cnrm  = (float*)take(EC*4);
  float* zbuf  = (float*)take((size_t)HISTC*BN*2*4);
  float* sbuf  = (float*)take((size_t)HISTC*BN*2*4);
  float* hbuf  = (float*)take((size_t)BN*HIDC*4);
  float* cbuf  = (float*)take((size_t)BN*HIDC*4);
  float* xnb   = (float*)take((size_t)BN*4);

  hipMemsetAsync(deg,  0, Nn*4*3, stream);                 // deg,cnt,fillc adjacent
  hipMemsetAsync(hbuf, 0, (size_t)BN*HIDC*4*2, stream);    // h,c adjacent

  k_deg<<<EC/256, 256, 0, stream>>>(ei, deg, cnt);
  k_dis<<<Nn/256, 256, 0, stream>>>(deg, dis);
  k_scan<<<1, 1024, 0, stream>>>(cnt, ptr);
  k_fill<<<EC/256, 256, 0, stream>>>(ei, dis, ptr, fillc, csrc, cnrm);

  // history precompute: z,s then agg+sigmoid (xg in-place in sbuf), all 16 steps
  k_zs<false><<<(HISTC*BN)/256, 256, 0, stream>>>(pm25, nullptr, feat, cw, cb, zbuf, sbuf, 0);
  k_agg<<<(HISTC*BN)/256, 256, 0, stream>>>(ptr, csrc, cnrm, zbuf, sbuf);

  for (int t = 0; t < HISTC; ++t){
    k_step<false><<<BN/64, 256, 0, stream>>>(pm25, feat, sbuf + (size_t)t*BN*2,
        x2hw, x2hb, h2hw, h2hb, fcw, fcb, hbuf, cbuf, xnb, nullptr,
        t, (t == HISTC-1) ? 1 : 0);
  }
  for (int tp = 0; tp < PREDC; ++tp){
    int t = HISTC + tp;
    k_zs<true><<<BN/256, 256, 0, stream>>>(pm25, xnb, feat, cw, cb, zbuf, sbuf, t);
    k_agg<<<BN/256, 256, 0, stream>>>(ptr, csrc, cnrm, zbuf, sbuf);
    k_step<true><<<BN/64, 256, 0, stream>>>(pm25, feat, sbuf,
        x2hw, x2hb, h2hw, h2hb, fcw, fcb, hbuf, cbuf, xnb, out + (size_t)tp*Nn,
        t, 1);
  }
}